// Round 1
// baseline (795.883 us; speedup 1.0000x reference)
//
#include <hip/hip_runtime.h>
#include <hip/hip_bf16.h>
#include <math.h>

#define NSP 8000      // 20*20*20 spatial
#define CIN 64

// ---------------------------------------------------------------------------
// Conv kernel: computes all 80 output channels (Q 0..7, K 8..15, V 16..79)
// O layout: (b, 80, 8000)
// ---------------------------------------------------------------------------
__global__ __launch_bounds__(256) void conv3_kernel(
    const float* __restrict__ x,
    const float* __restrict__ wq, const float* __restrict__ bq,
    const float* __restrict__ wk, const float* __restrict__ bk,
    const float* __restrict__ wv, const float* __restrict__ bv,
    float* __restrict__ O)
{
    const int tile = blockIdx.x;           // 0..31 spatial tiles of 256
    const int g    = blockIdx.y;           // 0..9 channel groups of 8
    const int b    = blockIdx.z;           // 0..1
    const int s    = tile * 256 + threadIdx.x;
    const bool alive = (s < NSP);
    const int ss = alive ? s : 0;
    const int z  = ss / 400;
    const int r0 = ss - z * 400;
    const int y  = r0 / 20;
    const int xx = r0 - y * 20;

    const float* w; const float* bias; int ob;
    if (g == 0)      { w = wq;                     bias = bq;             ob = 0; }
    else if (g == 1) { w = wk;                     bias = bk;             ob = 8; }
    else             { w = wv + (g - 2) * 8 * 1728; bias = bv + (g - 2) * 8; ob = 16 + (g - 2) * 8; }

    float acc[8];
    #pragma unroll
    for (int c = 0; c < 8; ++c) acc[c] = bias[c];

    const float* xb = x + (size_t)b * CIN * NSP;

    for (int ci = 0; ci < CIN; ++ci) {
        const float* xc = xb + ci * NSP;
        const float* wc = w + ci * 27;        // w[co][ci][k], co stride 1728
        #pragma unroll
        for (int dz = 0; dz < 3; ++dz) {
            const int zz = z + dz - 1;
            const bool vz = (unsigned)zz < 20u;
            #pragma unroll
            for (int dy = 0; dy < 3; ++dy) {
                const int yy = y + dy - 1;
                const bool vy = (unsigned)yy < 20u;
                #pragma unroll
                for (int dx = 0; dx < 3; ++dx) {
                    const int xq = xx + dx - 1;
                    const bool vx = (unsigned)xq < 20u;
                    const int k = (dz * 3 + dy) * 3 + dx;
                    const float xval = (vz && vy && vx) ? xc[zz * 400 + yy * 20 + xq] : 0.0f;
                    #pragma unroll
                    for (int c = 0; c < 8; ++c)
                        acc[c] = fmaf(xval, wc[c * 1728 + k], acc[c]);
                }
            }
        }
    }
    if (alive) {
        float* op = O + ((size_t)b * 80 + ob) * NSP + s;
        #pragma unroll
        for (int c = 0; c < 8; ++c) op[c * NSP] = acc[c];
    }
}

// ---------------------------------------------------------------------------
// Flash-attention kernel. TI=64 rows per block, TJ=64 per tile, 256 threads.
// Score role: si = t>>2 (row), jq = t&3 (16-col chunk)   [same-wave reduce]
// PV role:    ig = t&15 (4 rows), cg = t>>4 (4 channels) [4x4 register block]
// ---------------------------------------------------------------------------
#define TI 64
#define TJ 64

__global__ __launch_bounds__(256) void attn_kernel(
    const float* __restrict__ O, float* __restrict__ out)
{
    const int b  = blockIdx.y;
    const int i0 = blockIdx.x * TI;
    const float* Q = O + (size_t)b * 80 * NSP;
    const float* K = Q + 8 * NSP;
    const float* V = Q + 16 * NSP;

    __shared__ float k_lds[8][TJ];
    __shared__ float v_lds[TJ * 68];   // row stride 68 floats (16B-aligned rows), XOR-swizzled in c
    __shared__ float p_lds[TJ * 68];   // p^T: [j][i], row stride 68
    __shared__ float scale_lds[TI];
    __shared__ float l_lds[TI];

    const int t  = threadIdx.x;
    const int si = t >> 2;     // score row 0..63
    const int jq = t & 3;      // score col chunk 0..3
    const int ig = t & 15;     // pv row group 0..15
    const int cg = t >> 4;     // pv chan group 0..15

    float q[8];
    #pragma unroll
    for (int c = 0; c < 8; ++c) q[c] = Q[c * NSP + i0 + si];

    float m = -INFINITY, l = 0.0f;
    float acc[4][4];
    #pragma unroll
    for (int ii = 0; ii < 4; ++ii)
        #pragma unroll
        for (int cc = 0; cc < 4; ++cc) acc[ii][cc] = 0.0f;

    for (int jt = 0; jt < NSP / TJ; ++jt) {
        const int j0 = jt * TJ;

        // ---- stage K (512) and V (4096, swizzled transpose) ----
        #pragma unroll
        for (int r = 0; r < 2; ++r) {
            const int idx = t + r * 256;
            const int c = idx >> 6, j = idx & 63;
            k_lds[c][j] = K[c * NSP + j0 + j];
        }
        #pragma unroll
        for (int r = 0; r < 16; ++r) {
            const int idx = t + r * 256;
            const int c = idx >> 6, j = idx & 63;
            v_lds[j * 68 + (c ^ ((j >> 3) & 3))] = V[c * NSP + j0 + j];
        }
        __syncthreads();

        // ---- scores: 16 per thread ----
        float sloc[16];
        float lmax = -INFINITY;
        #pragma unroll
        for (int q4 = 0; q4 < 4; ++q4) {
            float s0 = 0.f, s1 = 0.f, s2 = 0.f, s3 = 0.f;
            #pragma unroll
            for (int c = 0; c < 8; ++c) {
                const float4 k4 = *(const float4*)&k_lds[c][jq * 16 + q4 * 4];
                s0 = fmaf(q[c], k4.x, s0);
                s1 = fmaf(q[c], k4.y, s1);
                s2 = fmaf(q[c], k4.z, s2);
                s3 = fmaf(q[c], k4.w, s3);
            }
            sloc[q4 * 4 + 0] = s0; sloc[q4 * 4 + 1] = s1;
            sloc[q4 * 4 + 2] = s2; sloc[q4 * 4 + 3] = s3;
            lmax = fmaxf(lmax, fmaxf(fmaxf(s0, s1), fmaxf(s2, s3)));
        }
        // reduce max across the 4 jq lanes (same wave, adjacent lanes)
        lmax = fmaxf(lmax, __shfl_xor(lmax, 1));
        lmax = fmaxf(lmax, __shfl_xor(lmax, 2));
        const float m_new = fmaxf(m, lmax);
        const float sc = __expf(m - m_new);
        float psum = 0.0f;
        #pragma unroll
        for (int jj = 0; jj < 16; ++jj) {
            const float p = __expf(sloc[jj] - m_new);
            psum += p;
            p_lds[(jq * 16 + jj) * 68 + si] = p;
        }
        psum += __shfl_xor(psum, 1);
        psum += __shfl_xor(psum, 2);
        l = l * sc + psum;
        m = m_new;
        if (jq == 0) scale_lds[si] = sc;
        __syncthreads();

        // ---- PV: 4 rows x 4 channels per thread ----
        {
            const float s0 = scale_lds[ig * 4 + 0];
            const float s1 = scale_lds[ig * 4 + 1];
            const float s2 = scale_lds[ig * 4 + 2];
            const float s3 = scale_lds[ig * 4 + 3];
            #pragma unroll
            for (int cc = 0; cc < 4; ++cc) {
                acc[0][cc] *= s0; acc[1][cc] *= s1;
                acc[2][cc] *= s2; acc[3][cc] *= s3;
            }
        }
        #pragma unroll
        for (int j8 = 0; j8 < 8; ++j8) {
            const int perm = j8 & 3;    // = (j>>3)&3, compile-time
            #pragma unroll
            for (int jj = 0; jj < 8; ++jj) {
                const int j = j8 * 8 + jj;
                const float4 p4 = *(const float4*)&p_lds[j * 68 + ig * 4];
                const float4 v4 = *(const float4*)&v_lds[j * 68 + cg * 4];
                const float pv[4] = {p4.x, p4.y, p4.z, p4.w};
                const float vv[4] = {v4.x, v4.y, v4.z, v4.w};
                #pragma unroll
                for (int ii = 0; ii < 4; ++ii)
                    #pragma unroll
                    for (int k = 0; k < 4; ++k)
                        acc[ii][k ^ perm] = fmaf(pv[ii], vv[k], acc[ii][k ^ perm]);
            }
        }
        __syncthreads();
    }

    // ---- epilogue ----
    if (jq == 0) l_lds[si] = l;
    __syncthreads();
    float* ob = out + (size_t)b * 64 * NSP;
    #pragma unroll
    for (int ii = 0; ii < 4; ++ii) {
        const float inv = 1.0f / l_lds[ig * 4 + ii];
        #pragma unroll
        for (int cc = 0; cc < 4; ++cc)
            ob[(cg * 4 + cc) * NSP + i0 + ig * 4 + ii] = acc[ii][cc] * inv;
    }
}

// ---------------------------------------------------------------------------
extern "C" void kernel_launch(void* const* d_in, const int* in_sizes, int n_in,
                              void* d_out, int out_size, void* d_ws, size_t ws_size,
                              hipStream_t stream) {
    const float* x  = (const float*)d_in[0];
    const float* wq = (const float*)d_in[1];
    const float* bq = (const float*)d_in[2];
    const float* wk = (const float*)d_in[3];
    const float* bk = (const float*)d_in[4];
    const float* wv = (const float*)d_in[5];
    const float* bv = (const float*)d_in[6];
    float* out = (float*)d_out;
    float* O   = (float*)d_ws;   // (2, 80, 8000) fp32 = 5.12 MB

    dim3 cgrid(32, 10, 2);
    conv3_kernel<<<cgrid, 256, 0, stream>>>(x, wq, bq, wk, bk, wv, bv, O);
    dim3 agrid(125, 2);
    attn_kernel<<<agrid, 256, 0, stream>>>(O, out);
}

// Round 2
// 269.416 us; speedup vs baseline: 2.9541x; 2.9541x over previous
//
#include <hip/hip_runtime.h>
#include <hip/hip_bf16.h>
#include <math.h>

#define NSP 8000      // 20*20*20 spatial
#define CIN 64

typedef __attribute__((ext_vector_type(8))) short bf16x8;
typedef __attribute__((ext_vector_type(4))) float f32x4;

__device__ __forceinline__ ushort f2bf(float f) {
    unsigned u = __float_as_uint(f);
    unsigned r = (u + 0x7fffu + ((u >> 16) & 1u)) >> 16;   // RNE
    return (ushort)r;
}

// ---------------------------------------------------------------------------
// Weight pre-conversion: wbf[ci][co(80)][kk(32)] bf16, kk = tap (27 real + 5 zero pad)
// co 0..7 = wq, 8..15 = wk, 16..79 = wv.  w layouts are (co, ci, 27).
// ---------------------------------------------------------------------------
__global__ __launch_bounds__(256) void wconv_kernel(
    const float* __restrict__ wq, const float* __restrict__ wk,
    const float* __restrict__ wv, ushort* __restrict__ wbf)
{
    const int ci   = blockIdx.y;                       // 0..63
    const int idx2 = blockIdx.x * 256 + threadIdx.x;   // 0..2559
    const int co   = idx2 >> 5;
    const int kk   = idx2 & 31;
    float v = 0.0f;
    if (kk < 27) {
        if (co < 8)       v = wq[(co * 64 + ci) * 27 + kk];
        else if (co < 16) v = wk[((co - 8) * 64 + ci) * 27 + kk];
        else              v = wv[((co - 16) * 64 + ci) * 27 + kk];
    }
    wbf[ci * 2560 + idx2] = f2bf(v);
}

// ---------------------------------------------------------------------------
// Conv via implicit-GEMM MFMA. One wave per block; s-tile = 16.
// D[80co][16s] = sum_{ci,tap} W[co][ci*32+tap] * x[ci][nbr(s,tap)]
// A-frag (W): lane holds A[co=l&15][k=8*(l>>4)+e]   (direct L2 b128 loads)
// B-frag (P): lane holds B[k=8*(l>>4)+e][s=l&15]    (register gather from x)
// ---------------------------------------------------------------------------
__global__ __launch_bounds__(64) void conv_mfma_kernel(
    const float* __restrict__ x, const ushort* __restrict__ wbf,
    const float* __restrict__ bq, const float* __restrict__ bk,
    const float* __restrict__ bv, float* __restrict__ O)
{
    const int l  = threadIdx.x;          // 0..63
    const int b  = blockIdx.y;
    const int s  = blockIdx.x * 16 + (l & 15);
    const int klo = (l >> 4) * 8;

    // spatial decode (loop-invariant)
    const int z  = s / 400;
    const int r0 = s - z * 400;
    const int y  = r0 / 20;
    const int xx = r0 - y * 20;

    int   pos[8];
    float wt[8];
    #pragma unroll
    for (int e = 0; e < 8; ++e) {
        const int tap = klo + e;
        bool ok = false; int p = 0;
        if (tap < 27) {
            const int dz = tap / 9, dy = (tap / 3) % 3, dx = tap % 3;
            const int zz = z + dz - 1, yy = y + dy - 1, xq = xx + dx - 1;
            ok = ((unsigned)zz < 20u) && ((unsigned)yy < 20u) && ((unsigned)xq < 20u);
            p  = ok ? (zz * 400 + yy * 20 + xq) : 0;
        }
        pos[e] = p;
        wt[e]  = ok ? 1.0f : 0.0f;
    }

    const float*  xb = x + (size_t)b * CIN * NSP;
    const ushort* wl = wbf + (l & 15) * 32 + klo;

    f32x4 acc[5];
    #pragma unroll
    for (int ct = 0; ct < 5; ++ct) acc[ct] = (f32x4)0.0f;

    float  g[8];
    bf16x8 a[5];

    #define GATHER(CI, G) { const float* xp = xb + (CI) * NSP;            \
        _Pragma("unroll") for (int e = 0; e < 8; ++e) G[e] = xp[pos[e]] * wt[e]; }
    #define LOADA(CI, A) { const ushort* wp = wl + (CI) * 2560;           \
        _Pragma("unroll") for (int ct = 0; ct < 5; ++ct)                  \
            A[ct] = *(const bf16x8*)(wp + ct * 512); }
    #define CONSUME(G, A) { bf16x8 bfrag;                                 \
        _Pragma("unroll") for (int e = 0; e < 8; ++e) bfrag[e] = (short)f2bf(G[e]); \
        _Pragma("unroll") for (int ct = 0; ct < 5; ++ct)                  \
            acc[ct] = __builtin_amdgcn_mfma_f32_16x16x32_bf16(A[ct], bfrag, acc[ct], 0, 0, 0); }

    GATHER(0, g); LOADA(0, a);
    for (int ci = 0; ci < CIN - 1; ++ci) {
        float  gn[8];
        bf16x8 an[5];
        GATHER(ci + 1, gn); LOADA(ci + 1, an);
        CONSUME(g, a);
        #pragma unroll
        for (int e = 0; e < 8; ++e) g[e] = gn[e];
        #pragma unroll
        for (int ct = 0; ct < 5; ++ct) a[ct] = an[ct];
    }
    CONSUME(g, a);
    #undef GATHER
    #undef LOADA
    #undef CONSUME

    // epilogue: D[co][s], co = ct*16 + 4*(l>>4)+r, s = l&15 (coalesced)
    #pragma unroll
    for (int ct = 0; ct < 5; ++ct) {
        #pragma unroll
        for (int r = 0; r < 4; ++r) {
            const int co = ct * 16 + (l >> 4) * 4 + r;
            const float bias = (co < 8) ? bq[co] : ((co < 16) ? bk[co - 8] : bv[co - 16]);
            O[((size_t)b * 80 + co) * NSP + s] = acc[ct][r] + bias;
        }
    }
}

// ---------------------------------------------------------------------------
// Flash attention: TI=64 rows/block, TJ=64 per tile, 512 threads (8 waves).
// Scores fp32 VALU (d=8), softmax online, PV via bf16 MFMA:
//   D[c][i] = sum_j V[c][j] * P[i][j]  -> A=V (c x j), B=P^T (j x i)
// LDS tiles vt[c][j], p[i][j] bf16, XOR-swizzled (col ^ ((row&7)*8)).
// ---------------------------------------------------------------------------
__global__ __launch_bounds__(512) void attn_kernel(
    const float* __restrict__ O, float* __restrict__ out)
{
    const int b  = blockIdx.y;
    const int i0 = blockIdx.x * 64;
    const float* Q = O + (size_t)b * 80 * NSP;
    const float* K = Q + 8 * NSP;
    const float* V = Q + 16 * NSP;

    __shared__ float  k_lds[8][64];
    __shared__ ushort vt[64 * 64];
    __shared__ ushort p_lds[64 * 64];
    __shared__ float  scale_lds[64];
    __shared__ float  l_lds[64];

    const int t = threadIdx.x;
    const int l = t & 63;
    const int w = t >> 6;

    // score role
    const int si = t >> 3;       // 0..63
    const int jq = t & 7;        // 8-col chunk
    // PV role
    const int itile = w >> 1;           // 0..3
    const int ct0   = (w & 1) * 2;      // c-tile base (x16)
    // stage role
    const int vc = t >> 3;              // 0..63
    const int vj = (t & 7) * 8;
    const int kc = t >> 6;              // 0..7
    const int kj = t & 63;

    float q[8];
    #pragma unroll
    for (int c = 0; c < 8; ++c) q[c] = Q[c * NSP + i0 + si];

    float m = -INFINITY, lsum = 0.0f;
    f32x4 acc[2];
    acc[0] = (f32x4)0.0f; acc[1] = (f32x4)0.0f;

    const int swz  = (l & 7) << 3;       // MFMA-read swizzle (row&7)*8
    const int lj   = (l >> 4) << 3;      // k-offset within 32

    for (int jt = 0; jt < NSP / 64; ++jt) {
        const int j0 = jt * 64;

        // ---- stage K (fp32) and V (bf16, swizzled) ----
        k_lds[kc][kj] = K[kc * NSP + j0 + kj];
        {
            const float4 va = *(const float4*)&V[vc * NSP + j0 + vj];
            const float4 vb = *(const float4*)&V[vc * NSP + j0 + vj + 4];
            ushort tmp[8] = { f2bf(va.x), f2bf(va.y), f2bf(va.z), f2bf(va.w),
                              f2bf(vb.x), f2bf(vb.y), f2bf(vb.z), f2bf(vb.w) };
            const int slot = (vj >> 3) ^ (vc & 7);
            *(uint4*)&vt[vc * 64 + slot * 8] = *(const uint4*)tmp;
        }
        __syncthreads();

        // ---- scores (fp32) + online softmax ----
        float sl[8];
        #pragma unroll
        for (int u = 0; u < 8; ++u) sl[u] = 0.0f;
        #pragma unroll
        for (int c = 0; c < 8; ++c) {
            const float qq = q[c];
            const float4 ka = *(const float4*)&k_lds[c][jq * 8];
            const float4 kb = *(const float4*)&k_lds[c][jq * 8 + 4];
            sl[0] = fmaf(qq, ka.x, sl[0]); sl[1] = fmaf(qq, ka.y, sl[1]);
            sl[2] = fmaf(qq, ka.z, sl[2]); sl[3] = fmaf(qq, ka.w, sl[3]);
            sl[4] = fmaf(qq, kb.x, sl[4]); sl[5] = fmaf(qq, kb.y, sl[5]);
            sl[6] = fmaf(qq, kb.z, sl[6]); sl[7] = fmaf(qq, kb.w, sl[7]);
        }
        float lmax = sl[0];
        #pragma unroll
        for (int u = 1; u < 8; ++u) lmax = fmaxf(lmax, sl[u]);
        lmax = fmaxf(lmax, __shfl_xor(lmax, 1));
        lmax = fmaxf(lmax, __shfl_xor(lmax, 2));
        lmax = fmaxf(lmax, __shfl_xor(lmax, 4));
        const float mn = fmaxf(m, lmax);
        const float sc = __expf(m - mn);
        float ps = 0.0f;
        ushort pb[8];
        #pragma unroll
        for (int u = 0; u < 8; ++u) {
            const float p = __expf(sl[u] - mn);
            ps += p;
            pb[u] = f2bf(p);
        }
        ps += __shfl_xor(ps, 1);
        ps += __shfl_xor(ps, 2);
        ps += __shfl_xor(ps, 4);
        lsum = lsum * sc + ps;
        m = mn;
        if (jq == 0) scale_lds[si] = sc;
        {
            const int slot = jq ^ (si & 7);
            *(uint4*)&p_lds[si * 64 + slot * 8] = *(const uint4*)pb;
        }
        __syncthreads();

        // ---- PV via MFMA ----
        {
            const float scr = scale_lds[itile * 16 + (l & 15)];
            #pragma unroll
            for (int r = 0; r < 4; ++r) { acc[0][r] *= scr; acc[1][r] *= scr; }
            const int irow = itile * 16 + (l & 15);
            #pragma unroll
            for (int js = 0; js < 2; ++js) {
                const int jcol = js * 32 + lj;
                const bf16x8 pbf = *(const bf16x8*)&p_lds[irow * 64 + (jcol ^ swz)];
                #pragma unroll
                for (int cc = 0; cc < 2; ++cc) {
                    const int crow = (ct0 + cc) * 16 + (l & 15);
                    const bf16x8 vbf = *(const bf16x8*)&vt[crow * 64 + (jcol ^ swz)];
                    acc[cc] = __builtin_amdgcn_mfma_f32_16x16x32_bf16(vbf, pbf, acc[cc], 0, 0, 0);
                }
            }
        }
        __syncthreads();
    }

    if (jq == 0) l_lds[si] = lsum;
    __syncthreads();

    const float linv = 1.0f / l_lds[itile * 16 + (l & 15)];
    float* ob = out + (size_t)b * 64 * NSP;
    #pragma unroll
    for (int cc = 0; cc < 2; ++cc) {
        #pragma unroll
        for (int r = 0; r < 4; ++r) {
            const int c = (ct0 + cc) * 16 + (l >> 4) * 4 + r;
            ob[(size_t)c * NSP + i0 + itile * 16 + (l & 15)] = acc[cc][r] * linv;
        }
    }
}

// ---------------------------------------------------------------------------
extern "C" void kernel_launch(void* const* d_in, const int* in_sizes, int n_in,
                              void* d_out, int out_size, void* d_ws, size_t ws_size,
                              hipStream_t stream) {
    const float* x  = (const float*)d_in[0];
    const float* wq = (const float*)d_in[1];
    const float* bq = (const float*)d_in[2];
    const float* wk = (const float*)d_in[3];
    const float* bk = (const float*)d_in[4];
    const float* wv = (const float*)d_in[5];
    const float* bv = (const float*)d_in[6];
    float* out = (float*)d_out;

    ushort* wbf = (ushort*)d_ws;                       // 64*80*32 bf16 = 320 KB
    float*  O   = (float*)((char*)d_ws + 327680);      // (2, 80, 8000) fp32 = 5.12 MB

    wconv_kernel<<<dim3(10, 64), 256, 0, stream>>>(wq, wk, wv, wbf);
    conv_mfma_kernel<<<dim3(500, 2), 64, 0, stream>>>(x, wbf, bq, bk, bv, O);
    attn_kernel<<<dim3(125, 2), 512, 0, stream>>>(O, out);
}

// Round 4
// 191.241 us; speedup vs baseline: 4.1617x; 1.4088x over previous
//
#include <hip/hip_runtime.h>
#include <hip/hip_bf16.h>
#include <math.h>

#define NSP 8000      // 20*20*20 spatial
#define CIN 64
#define LOG2E 1.4426950408889634f

typedef __attribute__((ext_vector_type(8)))  short    bf16x8;
typedef __attribute__((ext_vector_type(4)))  float    f32x4;
typedef __attribute__((ext_vector_type(16))) float    f32x16;
typedef __attribute__((ext_vector_type(8)))  _Float16 f16x8;
typedef __attribute__((ext_vector_type(2)))  __fp16   fp16x2;

__device__ __forceinline__ ushort f2bf(float f) {
    unsigned u = __float_as_uint(f);
    unsigned r = (u + 0x7fffu + ((u >> 16) & 1u)) >> 16;   // RNE
    return (ushort)r;
}

// ---------------------------------------------------------------------------
// Weight pre-conversion: wbf[ci][co(80)][kk(32)] bf16 (27 taps + 5 zero pad)
// ---------------------------------------------------------------------------
__global__ __launch_bounds__(256) void wconv_kernel(
    const float* __restrict__ wq, const float* __restrict__ wk,
    const float* __restrict__ wv, ushort* __restrict__ wbf)
{
    const int ci   = blockIdx.y;
    const int idx2 = blockIdx.x * 256 + threadIdx.x;   // 0..2559
    const int co   = idx2 >> 5;
    const int kk   = idx2 & 31;
    float v = 0.0f;
    if (kk < 27) {
        if (co < 8)       v = wq[(co * 64 + ci) * 27 + kk];
        else if (co < 16) v = wk[((co - 8) * 64 + ci) * 27 + kk];
        else              v = wv[((co - 16) * 64 + ci) * 27 + kk];
    }
    wbf[ci * 2560 + idx2] = f2bf(v);
}

// ---------------------------------------------------------------------------
// Conv implicit-GEMM MFMA, 4-way ci-split (4 waves/block, LDS combine).
// Writes Q (f16, pre-scaled by log2e), K (f16), V (f16) directly.
// ---------------------------------------------------------------------------
__global__ __launch_bounds__(256) void conv_mfma_kernel(
    const float* __restrict__ x, const ushort* __restrict__ wbf,
    const float* __restrict__ bq, const float* __restrict__ bk,
    const float* __restrict__ bv,
    _Float16* __restrict__ Qg, _Float16* __restrict__ Kg, _Float16* __restrict__ Vg)
{
    const int t = threadIdx.x;
    const int l = t & 63;
    const int w = t >> 6;               // ci-split 0..3
    const int b = blockIdx.y;
    const int s = blockIdx.x * 16 + (l & 15);
    const int klo = (l >> 4) * 8;

    const int z  = s / 400;
    const int r0 = s - z * 400;
    const int y  = r0 / 20;
    const int xx = r0 - y * 20;

    int   pos[8];
    float wt[8];
    #pragma unroll
    for (int e = 0; e < 8; ++e) {
        const int tap = klo + e;
        bool ok = false; int p = 0;
        if (tap < 27) {
            const int dz = tap / 9, dy = (tap / 3) % 3, dx = tap % 3;
            const int zz = z + dz - 1, yy = y + dy - 1, xq = xx + dx - 1;
            ok = ((unsigned)zz < 20u) && ((unsigned)yy < 20u) && ((unsigned)xq < 20u);
            p  = ok ? (zz * 400 + yy * 20 + xq) : 0;
        }
        pos[e] = p;
        wt[e]  = ok ? 1.0f : 0.0f;
    }

    const float*  xb = x + (size_t)b * CIN * NSP;
    const ushort* wl = wbf + (l & 15) * 32 + klo;
    const int c0 = w * 16;

    f32x4 acc[5];
    #pragma unroll
    for (int ct = 0; ct < 5; ++ct) acc[ct] = (f32x4)0.0f;

    float  g[8];
    bf16x8 a[5];

    #define GATHER(CI, G) { const float* xp = xb + (CI) * NSP;            \
        _Pragma("unroll") for (int e = 0; e < 8; ++e) G[e] = xp[pos[e]] * wt[e]; }
    #define LOADA(CI, A) { const ushort* wp = wl + (CI) * 2560;           \
        _Pragma("unroll") for (int ct = 0; ct < 5; ++ct)                  \
            A[ct] = *(const bf16x8*)(wp + ct * 512); }
    #define CONSUME(G, A) { bf16x8 bfrag;                                 \
        _Pragma("unroll") for (int e = 0; e < 8; ++e) bfrag[e] = (short)f2bf(G[e]); \
        _Pragma("unroll") for (int ct = 0; ct < 5; ++ct)                  \
            acc[ct] = __builtin_amdgcn_mfma_f32_16x16x32_bf16(A[ct], bfrag, acc[ct], 0, 0, 0); }

    GATHER(c0, g); LOADA(c0, a);
    for (int ci = c0; ci < c0 + 15; ++ci) {
        float  gn[8];
        bf16x8 an[5];
        GATHER(ci + 1, gn); LOADA(ci + 1, an);
        CONSUME(g, a);
        #pragma unroll
        for (int e = 0; e < 8; ++e) g[e] = gn[e];
        #pragma unroll
        for (int ct = 0; ct < 5; ++ct) a[ct] = an[ct];
    }
    CONSUME(g, a);
    #undef GATHER
    #undef LOADA
    #undef CONSUME

    __shared__ float lacc[3][64][20];
    if (w > 0) {
        #pragma unroll
        for (int ct = 0; ct < 5; ++ct)
            *(f32x4*)&lacc[w - 1][l][ct * 4] = acc[ct];
    }
    __syncthreads();
    if (w == 0) {
        #pragma unroll
        for (int ct = 0; ct < 5; ++ct) {
            #pragma unroll
            for (int r = 0; r < 4; ++r) {
                float v = acc[ct][r] + lacc[0][l][ct * 4 + r]
                        + lacc[1][l][ct * 4 + r] + lacc[2][l][ct * 4 + r];
                const int co = ct * 16 + (l >> 4) * 4 + r;
                if (co < 8)
                    Qg[((size_t)b * 8 + co) * NSP + s] = (_Float16)((v + bq[co]) * LOG2E);
                else if (co < 16)
                    Kg[((size_t)b * 8 + co - 8) * NSP + s] = (_Float16)(v + bk[co - 8]);
                else
                    Vg[((size_t)b * 64 + co - 16) * NSP + s] = (_Float16)(v + bv[co - 16]);
            }
        }
    }
}

// ---------------------------------------------------------------------------
// Flash attention: TI=32 rows/block, TJ=128/tile, 256 threads (4 waves).
// QK^T: mfma_f32_32x32x16_f16 (A=K, B=Q, K-dim=8 padded to 16) -> S[j][i].
// Softmax: in-lane (16 j per lane) + cross-wave partial-max via LDS.
// PV: mfma_f32_16x16x32_f16, V-fragments direct from global (L2-hot),
// P through 272B-padded-row LDS (conflict-free, no swizzle).
// ---------------------------------------------------------------------------
__global__ __launch_bounds__(256) void attn_kernel(
    const _Float16* __restrict__ Qg, const _Float16* __restrict__ Kg,
    const _Float16* __restrict__ Vg, float* __restrict__ out)
{
    const int t = threadIdx.x;
    const int l = t & 63;
    const int w = t >> 6;          // wave 0..3: QK j-subtile w, PV c-tile w
    const int b = blockIdx.y;
    const int i0 = blockIdx.x * 32;

    const _Float16* Qb = Qg + (size_t)b * 8 * NSP;
    const _Float16* Kb = Kg + (size_t)b * 8 * NSP;
    const _Float16* Vb = Vg + (size_t)b * 64 * NSP;

    __shared__ _Float16 p_lds[32 * 136];   // rows padded to 272B (17x16B slots)
    __shared__ float pmax_l[4][32];
    __shared__ float scale_l[32];
    __shared__ float lsum_l[4][32];

    const int il  = l & 31;   // i (QK role)
    const int i16 = l & 15;   // i (PV role)
    const int kg  = l >> 4;   // k-group (PV)
    const int kh  = l >> 5;   // k-half (QK)

    // Q fragment, loaded once (B operand: k=c, col=i)
    f16x8 qf = (f16x8)(_Float16)0.0f;
    if (l < 32) {
        #pragma unroll
        for (int e = 0; e < 8; ++e) qf[e] = Qb[(size_t)e * NSP + i0 + il];
    }

    float m = -INFINITY, lsum = 0.0f;
    f32x4 acc0 = (f32x4)0.0f, acc1 = (f32x4)0.0f;

    const f32x16 zero16 = (f32x16)0.0f;

    for (int jt = 0; jt < 63; ++jt) {
        const int j0 = jt * 128;

        // ---- phase A: V-fragment prefetch (global), K-fragment, QK MFMA ----
        f16x8 vf[4];
        {
            const _Float16* vp = Vb + (size_t)(w * 16 + i16) * NSP + j0 + kg * 8;
            #pragma unroll
            for (int ks = 0; ks < 4; ++ks)
                vf[ks] = *(const f16x8*)(vp + ks * 32);
        }
        f16x8 kf = (f16x8)(_Float16)0.0f;
        if (l < 32) {
            const _Float16* kp = Kb + j0 + w * 32 + il;
            #pragma unroll
            for (int e = 0; e < 8; ++e) kf[e] = kp[(size_t)e * NSP];
        }
        f32x16 sacc = __builtin_amdgcn_mfma_f32_32x32x16_f16(kf, qf, zero16, 0, 0, 0);
        if (jt == 62 && w >= 2) {       // tail tile: j >= 8000 for waves 2,3
            #pragma unroll
            for (int r = 0; r < 16; ++r) sacc[r] = -1e30f;
        }

        // ---- phase B: per-lane + cross-half max, write partial ----
        float pm = sacc[0];
        #pragma unroll
        for (int r = 1; r < 16; ++r) pm = fmaxf(pm, sacc[r]);
        pm = fmaxf(pm, __shfl_xor(pm, 32));
        if (l < 32) pmax_l[w][il] = pm;
        __syncthreads();

        // ---- phase C: global max, exp2, P->f16->LDS, l update ----
        const float mt = fmaxf(fmaxf(pmax_l[0][il], pmax_l[1][il]),
                               fmaxf(pmax_l[2][il], pmax_l[3][il]));
        const float mn = fmaxf(m, mt);
        const float sc = __builtin_amdgcn_exp2f(m - mn);
        if (w == 0 && l < 32) scale_l[il] = sc;
        float ps = 0.0f;
        #pragma unroll
        for (int g = 0; g < 4; ++g) {
            const float p0 = __builtin_amdgcn_exp2f(sacc[g * 4 + 0] - mn);
            const float p1 = __builtin_amdgcn_exp2f(sacc[g * 4 + 1] - mn);
            const float p2 = __builtin_amdgcn_exp2f(sacc[g * 4 + 2] - mn);
            const float p3 = __builtin_amdgcn_exp2f(sacc[g * 4 + 3] - mn);
            ps += (p0 + p1) + (p2 + p3);
            union { fp16x2 h[2]; uint2 u; } pk;
            pk.h[0] = __builtin_amdgcn_cvt_pkrtz(p0, p1);
            pk.h[1] = __builtin_amdgcn_cvt_pkrtz(p2, p3);
            const int jcol = w * 32 + g * 8 + kh * 4;   // j = (r&3)+8*(r>>2)+4*kh
            *(uint2*)&p_lds[il * 136 + jcol] = pk.u;
        }
        lsum = lsum * sc + ps;
        m = mn;
        __syncthreads();

        // ---- phase D: PV MFMA ----
        {
            const float s0 = scale_l[i16];
            const float s1 = scale_l[16 + i16];
            #pragma unroll
            for (int r = 0; r < 4; ++r) { acc0[r] *= s0; acc1[r] *= s1; }
        }
        #pragma unroll
        for (int ks = 0; ks < 4; ++ks) {
            const f16x8 pf0 = *(const f16x8*)&p_lds[i16 * 136 + ks * 32 + kg * 8];
            const f16x8 pf1 = *(const f16x8*)&p_lds[(16 + i16) * 136 + ks * 32 + kg * 8];
            acc0 = __builtin_amdgcn_mfma_f32_16x16x32_f16(vf[ks], pf0, acc0, 0, 0, 0);
            acc1 = __builtin_amdgcn_mfma_f32_16x16x32_f16(vf[ks], pf1, acc1, 0, 0, 0);
        }
    }

    // ---- epilogue: combine l partials, normalize, store ----
    lsum += __shfl_xor(lsum, 32);
    if (l < 32) lsum_l[w][il] = lsum;
    __syncthreads();
    const float lt0 = lsum_l[0][i16] + lsum_l[1][i16] + lsum_l[2][i16] + lsum_l[3][i16];
    const float lt1 = lsum_l[0][16 + i16] + lsum_l[1][16 + i16]
                    + lsum_l[2][16 + i16] + lsum_l[3][16 + i16];
    const float inv0 = 1.0f / lt0;
    const float inv1 = 1.0f / lt1;
    float* ob = out + (size_t)b * 64 * NSP;
    #pragma unroll
    for (int r = 0; r < 4; ++r) {
        const int c = w * 16 + kg * 4 + r;
        ob[(size_t)c * NSP + i0 + i16]      = acc0[r] * inv0;
        ob[(size_t)c * NSP + i0 + 16 + i16] = acc1[r] * inv1;
    }
}

// ---------------------------------------------------------------------------
extern "C" void kernel_launch(void* const* d_in, const int* in_sizes, int n_in,
                              void* d_out, int out_size, void* d_ws, size_t ws_size,
                              hipStream_t stream) {
    const float* x  = (const float*)d_in[0];
    const float* wq = (const float*)d_in[1];
    const float* bq = (const float*)d_in[2];
    const float* wk = (const float*)d_in[3];
    const float* bk = (const float*)d_in[4];
    const float* wv = (const float*)d_in[5];
    const float* bv = (const float*)d_in[6];
    float* out = (float*)d_out;

    ushort*   wbf = (ushort*)d_ws;                            // 327,680 B
    _Float16* Qg  = (_Float16*)((char*)d_ws + 327680);        // 256,000 B
    _Float16* Kg  = (_Float16*)((char*)d_ws + 583680);        // 256,000 B
    _Float16* Vg  = (_Float16*)((char*)d_ws + 839680);        // 2,048,000 B (+slack)

    wconv_kernel<<<dim3(10, 64), 256, 0, stream>>>(wq, wk, wv, wbf);
    conv_mfma_kernel<<<dim3(500, 2), 256, 0, stream>>>(x, wbf, bq, bk, bv, Qg, Kg, Vg);
    attn_kernel<<<dim3(250, 2), 256, 0, stream>>>(Qg, Kg, Vg, out);
}

// Round 5
// 162.315 us; speedup vs baseline: 4.9033x; 1.1782x over previous
//
#include <hip/hip_runtime.h>
#include <hip/hip_bf16.h>
#include <math.h>

#define NSP 8000      // 20*20*20 spatial
#define CIN 64
#define LOG2E 1.4426950408889634f

typedef __attribute__((ext_vector_type(8)))  short    bf16x8;
typedef __attribute__((ext_vector_type(4)))  float    f32x4;
typedef __attribute__((ext_vector_type(16))) float    f32x16;
typedef __attribute__((ext_vector_type(8)))  _Float16 f16x8;
typedef __attribute__((ext_vector_type(2)))  __fp16   fp16x2;

__device__ __forceinline__ ushort f2bf(float f) {
    unsigned u = __float_as_uint(f);
    unsigned r = (u + 0x7fffu + ((u >> 16) & 1u)) >> 16;   // RNE
    return (ushort)r;
}

// ---------------------------------------------------------------------------
// Weight pre-conversion: wbf[ci][co(80)][kk(32)] bf16 (27 taps + 5 zero pad)
// ---------------------------------------------------------------------------
__global__ __launch_bounds__(256) void wconv_kernel(
    const float* __restrict__ wq, const float* __restrict__ wk,
    const float* __restrict__ wv, ushort* __restrict__ wbf)
{
    const int ci   = blockIdx.y;
    const int idx2 = blockIdx.x * 256 + threadIdx.x;   // 0..2559
    const int co   = idx2 >> 5;
    const int kk   = idx2 & 31;
    float v = 0.0f;
    if (kk < 27) {
        if (co < 8)       v = wq[(co * 64 + ci) * 27 + kk];
        else if (co < 16) v = wk[((co - 8) * 64 + ci) * 27 + kk];
        else              v = wv[((co - 16) * 64 + ci) * 27 + kk];
    }
    wbf[ci * 2560 + idx2] = f2bf(v);
}

// ---------------------------------------------------------------------------
// Conv implicit-GEMM MFMA, 4-way ci-split (4 waves/block, LDS combine).
// Writes Qt[s][8c] (f16, pre-scaled by log2e), Kt[s][8c] (f16), V[c][s] (f16).
// ---------------------------------------------------------------------------
__global__ __launch_bounds__(256) void conv_mfma_kernel(
    const float* __restrict__ x, const ushort* __restrict__ wbf,
    const float* __restrict__ bq, const float* __restrict__ bk,
    const float* __restrict__ bv,
    _Float16* __restrict__ Qt, _Float16* __restrict__ Kt, _Float16* __restrict__ Vg)
{
    const int t = threadIdx.x;
    const int l = t & 63;
    const int w = t >> 6;               // ci-split 0..3
    const int b = blockIdx.y;
    const int s = blockIdx.x * 16 + (l & 15);
    const int klo = (l >> 4) * 8;

    const int z  = s / 400;
    const int r0 = s - z * 400;
    const int y  = r0 / 20;
    const int xx = r0 - y * 20;

    int   pos[8];
    float wt[8];
    #pragma unroll
    for (int e = 0; e < 8; ++e) {
        const int tap = klo + e;
        bool ok = false; int p = 0;
        if (tap < 27) {
            const int dz = tap / 9, dy = (tap / 3) % 3, dx = tap % 3;
            const int zz = z + dz - 1, yy = y + dy - 1, xq = xx + dx - 1;
            ok = ((unsigned)zz < 20u) && ((unsigned)yy < 20u) && ((unsigned)xq < 20u);
            p  = ok ? (zz * 400 + yy * 20 + xq) : 0;
        }
        pos[e] = p;
        wt[e]  = ok ? 1.0f : 0.0f;
    }

    const float*  xb = x + (size_t)b * CIN * NSP;
    const ushort* wl = wbf + (l & 15) * 32 + klo;
    const int c0 = w * 16;

    f32x4 acc[5];
    #pragma unroll
    for (int ct = 0; ct < 5; ++ct) acc[ct] = (f32x4)0.0f;

    float  g[8];
    bf16x8 a[5];

    #define GATHER(CI, G) { const float* xp = xb + (CI) * NSP;            \
        _Pragma("unroll") for (int e = 0; e < 8; ++e) G[e] = xp[pos[e]] * wt[e]; }
    #define LOADA(CI, A) { const ushort* wp = wl + (CI) * 2560;           \
        _Pragma("unroll") for (int ct = 0; ct < 5; ++ct)                  \
            A[ct] = *(const bf16x8*)(wp + ct * 512); }
    #define CONSUME(G, A) { bf16x8 bfrag;                                 \
        _Pragma("unroll") for (int e = 0; e < 8; ++e) bfrag[e] = (short)f2bf(G[e]); \
        _Pragma("unroll") for (int ct = 0; ct < 5; ++ct)                  \
            acc[ct] = __builtin_amdgcn_mfma_f32_16x16x32_bf16(A[ct], bfrag, acc[ct], 0, 0, 0); }

    GATHER(c0, g); LOADA(c0, a);
    for (int ci = c0; ci < c0 + 15; ++ci) {
        float  gn[8];
        bf16x8 an[5];
        GATHER(ci + 1, gn); LOADA(ci + 1, an);
        CONSUME(g, a);
        #pragma unroll
        for (int e = 0; e < 8; ++e) g[e] = gn[e];
        #pragma unroll
        for (int ct = 0; ct < 5; ++ct) a[ct] = an[ct];
    }
    CONSUME(g, a);
    #undef GATHER
    #undef LOADA
    #undef CONSUME

    __shared__ float lacc[3][64][20];
    if (w > 0) {
        #pragma unroll
        for (int ct = 0; ct < 5; ++ct)
            *(f32x4*)&lacc[w - 1][l][ct * 4] = acc[ct];
    }
    __syncthreads();
    if (w == 0) {
        #pragma unroll
        for (int ct = 0; ct < 5; ++ct) {
            #pragma unroll
            for (int r = 0; r < 4; ++r) {
                float v = acc[ct][r] + lacc[0][l][ct * 4 + r]
                        + lacc[1][l][ct * 4 + r] + lacc[2][l][ct * 4 + r];
                const int co = ct * 16 + (l >> 4) * 4 + r;
                if (co < 8)
                    Qt[((size_t)b * NSP + s) * 8 + co] = (_Float16)((v + bq[co]) * LOG2E);
                else if (co < 16)
                    Kt[((size_t)b * NSP + s) * 8 + (co - 8)] = (_Float16)(v + bk[co - 8]);
                else
                    Vg[((size_t)b * 64 + co - 16) * NSP + s] = (_Float16)(v + bv[co - 16]);
            }
        }
    }
}

// ---------------------------------------------------------------------------
// Barrier-free split-j flash attention.
// Block = 512 threads = 8 independent waves; all share i-tile of 32 rows.
// Wave w handles j-tiles {w, w+8, ...} of 250 tiles (32 j each).
// Per tile (within-wave only):
//   QK: mfma_32x32x16_f16 (A=Kt row-frag, B=Qt col-frag, hi-half k zeroed)
//   softmax: in-lane 16 + shfl_xor(32); defer-max (THR=8, log2 units)
//   P -> wave-private LDS (f16, 36-half padded rows), lgkmcnt fence only
//   PV: 4x mfma_32x32x16_f16, V frags direct from global (L2-hot)
// End: single LDS merge of 8 per-wave (m, l, acc) partials.
// ---------------------------------------------------------------------------
__global__ __launch_bounds__(512, 4) void attn_kernel(
    const _Float16* __restrict__ Qt, const _Float16* __restrict__ Kt,
    const _Float16* __restrict__ Vg, float* __restrict__ out)
{
    const int t  = threadIdx.x;
    const int l  = t & 63;
    const int w  = t >> 6;          // j-split 0..7
    const int b  = blockIdx.y;
    const int i0 = blockIdx.x * 32;
    const int il = l & 31;
    const int hi = l >> 5;

    const _Float16* Qtb = Qt + (size_t)b * NSP * 8;
    const _Float16* Ktb = Kt + (size_t)b * NSP * 8;
    const _Float16* Vb  = Vg + (size_t)b * 64 * NSP;

    __shared__ __align__(16) char smem[34816];
    _Float16* p_base = (_Float16*)smem;           // [8][32][36] f16 (18432 B)
    float*    mrg    = (float*)smem;              // [8][32][32] f32 (32768 B, aliases p)
    float*    mml    = (float*)(smem + 32768);    // [8][32]
    float*    lsm    = (float*)(smem + 33792);    // [8][32]

    _Float16* pw = p_base + w * 1152;             // wave-private P tile

    f16x8 qf = (f16x8)(_Float16)0.0f;
    if (l < 32) qf = *(const f16x8*)&Qtb[(size_t)(i0 + il) * 8];

    float m = -INFINITY, lsum = 0.0f;
    f32x16 acc0 = (f32x16)0.0f, acc1 = (f32x16)0.0f;
    const f32x16 zero16 = (f32x16)0.0f;

    for (int jt = w; jt < 250; jt += 8) {
        const int j0 = jt * 32;

        // K fragment: A[row=j][k=c], hi half (k=8..15) zero
        f16x8 kf = (f16x8)(_Float16)0.0f;
        if (l < 32) kf = *(const f16x8*)&Ktb[(size_t)(j0 + il) * 8];

        // V fragments: A[row=c][k=j], c = ct*32+il, j = j0 + ks*16 + 8*hi + e
        f16x8 vf0k0 = *(const f16x8*)&Vb[(size_t)(il)      * NSP + j0 + 8 * hi];
        f16x8 vf0k1 = *(const f16x8*)&Vb[(size_t)(il)      * NSP + j0 + 16 + 8 * hi];
        f16x8 vf1k0 = *(const f16x8*)&Vb[(size_t)(32 + il) * NSP + j0 + 8 * hi];
        f16x8 vf1k1 = *(const f16x8*)&Vb[(size_t)(32 + il) * NSP + j0 + 16 + 8 * hi];

        f32x16 sacc = __builtin_amdgcn_mfma_f32_32x32x16_f16(kf, qf, zero16, 0, 0, 0);

        // row max over this tile (lane holds 16 j's for col i=il)
        float pm = sacc[0];
        #pragma unroll
        for (int r = 1; r < 16; ++r) pm = fmaxf(pm, sacc[r]);
        pm = fmaxf(pm, __shfl_xor(pm, 32));

        // defer-max: rescale only when max grows by > 8 (log2 units)
        if (__any(pm > m + 8.0f)) {
            const float mn = fmaxf(m, pm);
            const float sc = __builtin_amdgcn_exp2f(m - mn);
            #pragma unroll
            for (int r = 0; r < 16; ++r) { acc0[r] *= sc; acc1[r] *= sc; }
            lsum *= sc;
            m = mn;
        }

        float ps = 0.0f;
        float pr[16];
        #pragma unroll
        for (int r = 0; r < 16; ++r) {
            pr[r] = __builtin_amdgcn_exp2f(sacc[r] - m);
            ps += pr[r];
        }
        ps += __shfl_xor(ps, 32);
        lsum += ps;

        // P -> wave-private LDS: j = 4*hi + 8*g + (r&3), row = i = il
        #pragma unroll
        for (int g = 0; g < 4; ++g) {
            union { fp16x2 h[2]; uint2 u; } pk;
            pk.h[0] = __builtin_amdgcn_cvt_pkrtz(pr[g * 4 + 0], pr[g * 4 + 1]);
            pk.h[1] = __builtin_amdgcn_cvt_pkrtz(pr[g * 4 + 2], pr[g * 4 + 3]);
            *(uint2*)(pw + il * 36 + g * 8 + hi * 4) = pk.u;
        }
        asm volatile("s_waitcnt lgkmcnt(0)" ::: "memory");
        __builtin_amdgcn_sched_barrier(0);

        // PV: B[k=j][col=i] = P, read 16B at [il][ks*16 + 8*hi]
        {
            const f16x8 pf0 = *(const f16x8*)(pw + il * 36 + 8 * hi);
            acc0 = __builtin_amdgcn_mfma_f32_32x32x16_f16(vf0k0, pf0, acc0, 0, 0, 0);
            acc1 = __builtin_amdgcn_mfma_f32_32x32x16_f16(vf1k0, pf0, acc1, 0, 0, 0);
            const f16x8 pf1 = *(const f16x8*)(pw + il * 36 + 16 + 8 * hi);
            acc0 = __builtin_amdgcn_mfma_f32_32x32x16_f16(vf0k1, pf1, acc0, 0, 0, 0);
            acc1 = __builtin_amdgcn_mfma_f32_32x32x16_f16(vf1k1, pf1, acc1, 0, 0, 0);
        }
    }

    // ---- merge 8 per-wave partials ----
    __syncthreads();                      // all waves done with p region
    if (l < 32) mml[w * 32 + il] = m;
    __syncthreads();
    float gm = mml[il];
    #pragma unroll
    for (int ww = 1; ww < 8; ++ww) gm = fmaxf(gm, mml[ww * 32 + il]);
    const float f = __builtin_amdgcn_exp2f(m - gm);
    if (l < 32) lsm[w * 32 + il] = lsum * f;
    #pragma unroll
    for (int r = 0; r < 16; ++r) { acc0[r] *= f; acc1[r] *= f; }

    float* ob = out + (size_t)b * 64 * NSP + i0;

    // ct = 0 (c 0..31)
    #pragma unroll
    for (int r = 0; r < 16; ++r) {
        const int cl = (r & 3) + 8 * (r >> 2) + 4 * hi;
        mrg[w * 1024 + cl * 32 + il] = acc0[r];
    }
    __syncthreads();
    #pragma unroll
    for (int rep = 0; rep < 2; ++rep) {
        const int e = t + rep * 512;
        const int c = e >> 5, i = e & 31;
        float s = 0.0f, lg = 0.0f;
        #pragma unroll
        for (int ww = 0; ww < 8; ++ww) {
            s  += mrg[ww * 1024 + c * 32 + i];
            lg += lsm[ww * 32 + i];
        }
        ob[(size_t)c * NSP + i] = s / lg;
    }
    __syncthreads();                      // protect mrg for ct=1 overwrite

    // ct = 1 (c 32..63)
    #pragma unroll
    for (int r = 0; r < 16; ++r) {
        const int cl = (r & 3) + 8 * (r >> 2) + 4 * hi;
        mrg[w * 1024 + cl * 32 + il] = acc1[r];
    }
    __syncthreads();
    #pragma unroll
    for (int rep = 0; rep < 2; ++rep) {
        const int e = t + rep * 512;
        const int c = e >> 5, i = e & 31;
        float s = 0.0f, lg = 0.0f;
        #pragma unroll
        for (int ww = 0; ww < 8; ++ww) {
            s  += mrg[ww * 1024 + c * 32 + i];
            lg += lsm[ww * 32 + i];
        }
        ob[(size_t)(32 + c) * NSP + i] = s / lg;
    }
}

// ---------------------------------------------------------------------------
extern "C" void kernel_launch(void* const* d_in, const int* in_sizes, int n_in,
                              void* d_out, int out_size, void* d_ws, size_t ws_size,
                              hipStream_t stream) {
    const float* x  = (const float*)d_in[0];
    const float* wq = (const float*)d_in[1];
    const float* bq = (const float*)d_in[2];
    const float* wk = (const float*)d_in[3];
    const float* bk = (const float*)d_in[4];
    const float* wv = (const float*)d_in[5];
    const float* bv = (const float*)d_in[6];
    float* out = (float*)d_out;

    ushort*   wbf = (ushort*)d_ws;                            // 327,680 B
    _Float16* Qt  = (_Float16*)((char*)d_ws + 327680);        // 256,000 B  [b][s][8c]
    _Float16* Kt  = (_Float16*)((char*)d_ws + 583680);        // 256,000 B  [b][s][8c]
    _Float16* Vg  = (_Float16*)((char*)d_ws + 839680);        // 2,048,000 B [b][c][s]

    wconv_kernel<<<dim3(10, 64), 256, 0, stream>>>(wq, wk, wv, wbf);
    conv_mfma_kernel<<<dim3(500, 2), 256, 0, stream>>>(x, wbf, bq, bk, bv, Qt, Kt, Vg);
    attn_kernel<<<dim3(250, 2), 512, 0, stream>>>(Qt, Kt, Vg, out);
}